// Round 3
// baseline (383.564 us; speedup 1.0000x reference)
//
#include <hip/hip_runtime.h>
#include <hip/hip_bf16.h>
#include <stdint.h>

#define B_ 32
#define S_ 8192
#define HD_ 256
#define HE_ 256
#define CHUNK 128
#define NCHUNK (S_/CHUNK)   /* 64 chunks per batch */
#define PSTRIDE 392         /* 256 num + m + d + 128 swe + 6 pad */

typedef __attribute__((ext_vector_type(8))) short bf16x8;
typedef __attribute__((ext_vector_type(4))) float f32x4;

__device__ __forceinline__ unsigned short f2bf(float f) {
  uint32_t u = __float_as_uint(f);
  u += 0x7FFFu + ((u >> 16) & 1u);          // round-to-nearest-even
  return (unsigned short)(u >> 16);
}
__device__ __forceinline__ float tanh_fast(float x) {
  // tanh(x) = 1 - 2/(exp(2x)+1); well-behaved at +/-inf, no NaN
  float e = __expf(2.0f * x);
  return 1.0f - 2.0f * __builtin_amdgcn_rcpf(e + 1.0f);
}

// ---------------- prep: qv[b,h] = q@Wa^T + Wa_b + Ua_b ; Ua -> bf16 ----------------
__global__ void prep_kernel(const float* __restrict__ query,
                            const float* __restrict__ Wa_w,
                            const float* __restrict__ Wa_b,
                            const float* __restrict__ Ua_w,
                            const float* __restrict__ Ua_b,
                            float* __restrict__ qv,
                            unsigned short* __restrict__ ua_bf) {
  const int blk = blockIdx.x, t = threadIdx.x;
  if (blk < B_) {
    __shared__ float qs[HD_];
    qs[t] = query[blk * HD_ + t];
    __syncthreads();
    const float* wr = Wa_w + (size_t)t * HD_;
    float s = Wa_b[t] + Ua_b[t];
#pragma unroll 8
    for (int d = 0; d < HD_; ++d) s += qs[d] * wr[d];
    qv[blk * HD_ + t] = s;
  } else {
    const int base = (blk - B_) * 2048 + t * 8;
    float4 v0 = *(const float4*)(Ua_w + base);
    float4 v1 = *(const float4*)(Ua_w + base + 4);
    uint4 pk;
    pk.x = (uint32_t)f2bf(v0.x) | ((uint32_t)f2bf(v0.y) << 16);
    pk.y = (uint32_t)f2bf(v0.z) | ((uint32_t)f2bf(v0.w) << 16);
    pk.z = (uint32_t)f2bf(v1.x) | ((uint32_t)f2bf(v1.y) << 16);
    pk.w = (uint32_t)f2bf(v1.z) | ((uint32_t)f2bf(v1.w) << 16);
    *(uint4*)(ua_bf + base) = pk;
  }
}

// ---------------- main: fused k_proj GEMM + tanh + score + softmax partial + context partial ----------------
__global__ __launch_bounds__(512)
__attribute__((amdgpu_waves_per_eu(4, 4)))
void main_kernel(const float* __restrict__ keys,
                 const float* __restrict__ qv,
                 const float* __restrict__ Va_w,
                 const unsigned short* __restrict__ ua_bf,
                 float* __restrict__ partials) {
  __shared__ float qvs[HD_];
  __shared__ float vas[HD_];
  __shared__ float ssc[CHUNK];
  __shared__ float swe[CHUNK];
  __shared__ float sred[2];
  __shared__ float num2[512];

  const int t = threadIdx.x;
  const int b = blockIdx.y;
  const int chunk = blockIdx.x;
  const int s0 = chunk * CHUNK;
  const int lane = t & 63;
  const int w = t >> 6;          // wave 0..7, owns rows w*16..w*16+15
  const int ln = lane & 15;
  const int hi = lane >> 4;

  if (t < HD_) { qvs[t] = qv[b * HD_ + t]; vas[t] = Va_w[t]; }

  // ---- A-fragments: direct global loads in MFMA layout (row = s0+w*16+ln) ----
  const float* arow = keys + ((size_t)b * S_ + s0 + w * 16 + ln) * HE_ + hi * 8;
  float4 ar0[8], ar1[8];
#pragma unroll
  for (int k = 0; k < 8; ++k) {
    ar0[k] = *(const float4*)(arow + k * 32);
    ar1[k] = *(const float4*)(arow + k * 32 + 4);
  }

  // ---- B prefetch nt=0 (Ua is L1/L2-hot) ----
  const unsigned short* ub = ua_bf + (size_t)ln * HE_ + hi * 8;
  bf16x8 bb[2][8];
#pragma unroll
  for (int k = 0; k < 8; ++k) bb[0][k] = *(const bf16x8*)(ub + k * 32);

  // ---- convert A fp32 -> bf16 fragments ----
  bf16x8 afr[8];
#pragma unroll
  for (int k = 0; k < 8; ++k) {
    bf16x8 v;
    v[0] = (short)f2bf(ar0[k].x); v[1] = (short)f2bf(ar0[k].y);
    v[2] = (short)f2bf(ar0[k].z); v[3] = (short)f2bf(ar0[k].w);
    v[4] = (short)f2bf(ar1[k].x); v[5] = (short)f2bf(ar1[k].y);
    v[6] = (short)f2bf(ar1[k].z); v[7] = (short)f2bf(ar1[k].w);
    afr[k] = v;
  }

  __syncthreads();   // qvs/vas ready (overlaps with loads above)

  // ---- MFMA over 16 nt-tiles, B double-buffered in regs (static index) ----
  float part[4] = {0.f, 0.f, 0.f, 0.f};
#pragma unroll
  for (int nt = 0; nt < 16; ++nt) {
    if (nt < 15) {
      const unsigned short* ubn = ub + (size_t)(nt + 1) * 16 * HE_;
#pragma unroll
      for (int k = 0; k < 8; ++k) bb[(nt + 1) & 1][k] = *(const bf16x8*)(ubn + k * 32);
    }
    f32x4 acc = {0.f, 0.f, 0.f, 0.f};
#pragma unroll
    for (int k = 0; k < 8; ++k)
      acc = __builtin_amdgcn_mfma_f32_16x16x32_bf16(afr[k], bb[nt & 1][k], acc, 0, 0, 0);
    const int h = nt * 16 + ln;
    const float va = vas[h];
    const float q = qvs[h];
#pragma unroll
    for (int r = 0; r < 4; ++r) part[r] += tanh_fast(acc[r] + q) * va;
  }

  // ---- reduce 16 h-columns per lane-group -> row score ----
#pragma unroll
  for (int r = 0; r < 4; ++r) {
    float v = part[r];
    v += __shfl_xor(v, 1, 64);
    v += __shfl_xor(v, 2, 64);
    v += __shfl_xor(v, 4, 64);
    v += __shfl_xor(v, 8, 64);
    if (ln == 0) ssc[w * 16 + hi * 4 + r] = v;
  }
  __syncthreads();

  // ---- block softmax over 128 scores (one wave) ----
  if (t < 64) {
    float a0 = ssc[t], a1 = ssc[t + 64];
    float v = fmaxf(a0, a1);
#pragma unroll
    for (int mm = 32; mm; mm >>= 1) v = fmaxf(v, __shfl_xor(v, mm, 64));
    float e0 = __expf(a0 - v);
    float e1 = __expf(a1 - v);
    swe[t] = e0; swe[t + 64] = e1;
    float s = e0 + e1;
#pragma unroll
    for (int mm = 32; mm; mm >>= 1) s += __shfl_xor(s, mm, 64);
    if (t == 0) { sred[0] = v; sred[1] = s; }
  }
  __syncthreads();

  // ---- context numerator: coalesced re-read of keys tile (L2/L3-hot) ----
  const int e = t & 255;
  const int rh = t >> 8;                     // row half: 0 or 1
  const float* kcol = keys + ((size_t)b * S_ + s0 + rh * 64) * HE_ + e;
  float num = 0.f;
#pragma unroll 8
  for (int i = 0; i < 64; ++i) num += swe[rh * 64 + i] * kcol[(size_t)i * HE_];
  num2[t] = num;
  __syncthreads();

  float* pp = partials + (size_t)(b * NCHUNK + chunk) * PSTRIDE;
  if (t < 256) pp[t] = num2[t] + num2[t + 256];
  else if (t < 384) pp[258 + (t - 256)] = swe[t - 256];
  if (t == 384) { pp[256] = sred[0]; pp[257] = sred[1]; }
}

// ---------------- combine: merge partials, write context + weights ----------------
__global__ void combine_kernel(const float* __restrict__ partials,
                               float* __restrict__ out) {
  __shared__ float sm[NCHUNK], ssd[NCHUNK], sscale[NCHUNK];
  const int b = blockIdx.x, t = threadIdx.x;   // 256 threads
  const float* pb = partials + (size_t)b * NCHUNK * PSTRIDE;
  if (t < NCHUNK) {
    sm[t]  = pb[(size_t)t * PSTRIDE + 256];
    ssd[t] = pb[(size_t)t * PSTRIDE + 257];
  }
  __syncthreads();
  float mb = -1e30f;
#pragma unroll
  for (int i = 0; i < NCHUNK; ++i) mb = fmaxf(mb, sm[i]);
  if (t < NCHUNK) sscale[t] = __expf(sm[t] - mb);
  __syncthreads();
  float denom = 0.f;
#pragma unroll
  for (int i = 0; i < NCHUNK; ++i) denom += ssd[i] * sscale[i];
  const float rd = 1.0f / denom;

  // context: thread t owns e=t
  float num = 0.f;
#pragma unroll 4
  for (int i = 0; i < NCHUNK; ++i) num += pb[(size_t)i * PSTRIDE + t] * sscale[i];
  out[b * HE_ + t] = num * rd;

  // weights from stored per-chunk swe: w = swe * sscale * rd
  float* wout = out + B_ * HE_ + (size_t)b * S_;
  for (int s = t; s < S_; s += 256) {
    int i = s >> 7, j = s & 127;
    wout[s] = pb[(size_t)i * PSTRIDE + 258 + j] * sscale[i] * rd;
  }
}

extern "C" void kernel_launch(void* const* d_in, const int* in_sizes, int n_in,
                              void* d_out, int out_size, void* d_ws, size_t ws_size,
                              hipStream_t stream) {
  const float* query = (const float*)d_in[0];
  const float* keys  = (const float*)d_in[1];
  const float* Wa_w  = (const float*)d_in[2];
  const float* Wa_b  = (const float*)d_in[3];
  const float* Ua_w  = (const float*)d_in[4];
  const float* Ua_b  = (const float*)d_in[5];
  const float* Va_w  = (const float*)d_in[6];
  // Va_b (d_in[7]) is a constant score shift: softmax-invariant, dropped.
  float* out = (float*)d_out;

  char* ws = (char*)d_ws;
  float* qv             = (float*)ws;                                 // 32 KB
  unsigned short* ua_bf = (unsigned short*)(ws + 32 * 1024);          // 128 KB
  float* partials       = (float*)(ws + 160 * 1024);                  // ~3.3 MB

  prep_kernel<<<64, 256, 0, stream>>>(query, Wa_w, Wa_b, Ua_w, Ua_b, qv, ua_bf);
  dim3 g(NCHUNK, B_);
  main_kernel<<<g, 512, 0, stream>>>(keys, qv, Va_w, ua_bf, partials);
  combine_kernel<<<B_, 256, 0, stream>>>(partials, out);
}

// Round 4
// 104.717 us; speedup vs baseline: 3.6629x; 3.6629x over previous
//
#include <hip/hip_runtime.h>
#include <hip/hip_bf16.h>
#include <stdint.h>

#define B_ 32
#define S_ 8192
#define HD_ 256
#define HE_ 256
#define CHUNK 256
#define MSTEPS 16            /* 16 rows per step */
#define NCHUNK (S_/CHUNK)    /* 32 chunks per batch */

typedef __attribute__((ext_vector_type(8))) short bf16x8;
typedef __attribute__((ext_vector_type(4))) float f32x4;

__device__ __forceinline__ unsigned short f2bf(float f) {
  uint32_t u = __float_as_uint(f);
  u += 0x7FFFu + ((u >> 16) & 1u);          // round-to-nearest-even
  return (unsigned short)(u >> 16);
}
__device__ __forceinline__ float bf2f(unsigned short h) {
  return __uint_as_float(((uint32_t)h) << 16);
}
__device__ __forceinline__ float tanh_fast(float x) {
  // tanh(x) = 1 - 2/(exp(2x)+1); well-behaved at +/-inf, no NaN
  float e = __expf(2.0f * x);
  return 1.0f - 2.0f * __builtin_amdgcn_rcpf(e + 1.0f);
}

// ---------------- prep: qv[b,h] = q@Wa^T + Wa_b + Ua_b ; Ua -> bf16 ----------------
__global__ void prep_kernel(const float* __restrict__ query,
                            const float* __restrict__ Wa_w,
                            const float* __restrict__ Wa_b,
                            const float* __restrict__ Ua_w,
                            const float* __restrict__ Ua_b,
                            float* __restrict__ qv,
                            unsigned short* __restrict__ ua_bf) {
  const int blk = blockIdx.x, t = threadIdx.x;
  if (blk < B_) {
    __shared__ float qs[HD_];
    qs[t] = query[blk * HD_ + t];
    __syncthreads();
    const float* wr = Wa_w + (size_t)t * HD_;
    float s = Wa_b[t] + Ua_b[t];
#pragma unroll 8
    for (int d = 0; d < HD_; ++d) s += qs[d] * wr[d];
    qv[blk * HD_ + t] = s;
  } else {
    const int base = (blk - B_) * 2048 + t * 8;
    float4 v0 = *(const float4*)(Ua_w + base);
    float4 v1 = *(const float4*)(Ua_w + base + 4);
    uint4 pk;
    pk.x = (uint32_t)f2bf(v0.x) | ((uint32_t)f2bf(v0.y) << 16);
    pk.y = (uint32_t)f2bf(v0.z) | ((uint32_t)f2bf(v0.w) << 16);
    pk.z = (uint32_t)f2bf(v1.x) | ((uint32_t)f2bf(v1.y) << 16);
    pk.w = (uint32_t)f2bf(v1.z) | ((uint32_t)f2bf(v1.w) << 16);
    *(uint4*)(ua_bf + base) = pk;
  }
}

// ---------------- main: fused k_proj GEMM + tanh + score-exp + context partial ----------------
// 512 threads = 8 waves. Wave w owns h-slice [32w, 32w+32) with Ua frags in regs.
// 16-row M-steps, double-buffered bf16 keys tile in LDS, keys read from HBM once.
__global__ __launch_bounds__(512)
__attribute__((amdgpu_waves_per_eu(4, 4)))
void main_kernel(const float* __restrict__ keys,
                 const float* __restrict__ qv,
                 const float* __restrict__ Va_w,
                 const unsigned short* __restrict__ ua_bf,
                 float* __restrict__ wexp_g,
                 float* __restrict__ partials) {
  __shared__ __align__(16) char kt[2 * MSTEPS * 512];   // 2 x (16 rows x 512B bf16), swizzled
  __shared__ float sc[16][9];                           // per-row, per-wave score partials
  __shared__ float swp[16];                             // per-row exp(score)
  __shared__ float num2[512];

  const int t = threadIdx.x;
  const int b = blockIdx.y;
  const int chunk = blockIdx.x;
  const int s0 = chunk * CHUNK;
  const int lane = t & 63;
  const int w = t >> 6;
  const int ln = lane & 15;
  const int hi = lane >> 4;

  // ---- B fragments: wave w's 32 h-cols, 2 nt tiles, read ONCE (64 VGPRs) ----
  const unsigned short* ub0 = ua_bf + (size_t)(w * 32 + ln) * HE_ + hi * 8;
  const unsigned short* ub1 = ub0 + 16 * HE_;
  bf16x8 bb0[8], bb1[8];
#pragma unroll
  for (int k = 0; k < 8; ++k) {
    bb0[k] = *(const bf16x8*)(ub0 + k * 32);
    bb1[k] = *(const bf16x8*)(ub1 + k * 32);
  }
  const float q0  = qv[b * HD_ + w * 32 + ln];
  const float q1  = qv[b * HD_ + w * 32 + 16 + ln];
  const float va0 = Va_w[w * 32 + ln];
  const float va1 = Va_w[w * 32 + 16 + ln];

  // ---- staging geometry: thread t handles one 16B bf16 chunk (8 elems) per step ----
  const int srow = t >> 5;            // 0..15
  const int scch = t & 31;            // 0..31 (16B chunks per 512B row)
  const float* ksrc = keys + ((size_t)b * S_ + s0 + srow) * HE_ + scch * 8;
  const int ldsoff = srow * 512 + ((scch * 16) ^ ((srow & 7) << 4));

  // ---- prologue: stage step 0 ----
  {
    float4 fa = *(const float4*)(ksrc);
    float4 fb = *(const float4*)(ksrc + 4);
    uint4 pk;
    pk.x = (uint32_t)f2bf(fa.x) | ((uint32_t)f2bf(fa.y) << 16);
    pk.y = (uint32_t)f2bf(fa.z) | ((uint32_t)f2bf(fa.w) << 16);
    pk.z = (uint32_t)f2bf(fb.x) | ((uint32_t)f2bf(fb.y) << 16);
    pk.w = (uint32_t)f2bf(fb.z) | ((uint32_t)f2bf(fb.w) << 16);
    *(uint4*)(kt + ldsoff) = pk;
  }
  __syncthreads();

  const int half = t >> 8;            // numerator row-half
  const int e2 = (t & 255) * 2;       // numerator column byte offset (bf16)
  const int asw = (ln & 7) << 4;      // A-frag row swizzle
  float num = 0.f;

  for (int i = 0; i < MSTEPS; ++i) {
    char* cur = kt + (i & 1) * (MSTEPS * 512);
    char* nxt = kt + ((i + 1) & 1) * (MSTEPS * 512);

    // issue next-step global loads early (T14: issue-early / write-late)
    float4 ga, gb;
    if (i + 1 < MSTEPS) {
      const float* kn = ksrc + (size_t)(i + 1) * 16 * HE_;
      ga = *(const float4*)(kn);
      gb = *(const float4*)(kn + 4);
    }

    // ---- MFMA: A-frags just-in-time from LDS; 2 h-tiles per wave ----
    f32x4 acc0 = {0.f, 0.f, 0.f, 0.f};
    f32x4 acc1 = {0.f, 0.f, 0.f, 0.f};
    const char* arow = cur + ln * 512;
#pragma unroll
    for (int k = 0; k < 8; ++k) {
      bf16x8 afr = *(const bf16x8*)(arow + ((k * 64 + hi * 16) ^ asw));
      acc0 = __builtin_amdgcn_mfma_f32_16x16x32_bf16(afr, bb0[k], acc0, 0, 0, 0);
      acc1 = __builtin_amdgcn_mfma_f32_16x16x32_bf16(afr, bb1[k], acc1, 0, 0, 0);
    }

    // ---- per-row partial over this wave's 32 h-cols ----
#pragma unroll
    for (int r = 0; r < 4; ++r) {
      float v = tanh_fast(acc0[r] + q0) * va0 + tanh_fast(acc1[r] + q1) * va1;
      v += __shfl_xor(v, 1, 64);
      v += __shfl_xor(v, 2, 64);
      v += __shfl_xor(v, 4, 64);
      v += __shfl_xor(v, 8, 64);
      if (ln == 0) sc[hi * 4 + r][w] = v;
    }
    __syncthreads();

    // ---- row score = sum over 8 waves; exp (no max shift: |score| <= 16) ----
    if (t < 16) {
      float s = sc[t][0];
#pragma unroll
      for (int ww = 1; ww < 8; ++ww) s += sc[t][ww];
      float e = __expf(s);
      swp[t] = e;
      wexp_g[(size_t)b * S_ + s0 + i * 16 + t] = e;
    }
    __syncthreads();

    // ---- stage-write next tile (other buffer) + context numerator (this buffer) ----
    if (i + 1 < MSTEPS) {
      uint4 pk;
      pk.x = (uint32_t)f2bf(ga.x) | ((uint32_t)f2bf(ga.y) << 16);
      pk.y = (uint32_t)f2bf(ga.z) | ((uint32_t)f2bf(ga.w) << 16);
      pk.z = (uint32_t)f2bf(gb.x) | ((uint32_t)f2bf(gb.y) << 16);
      pk.w = (uint32_t)f2bf(gb.z) | ((uint32_t)f2bf(gb.w) << 16);
      *(uint4*)(nxt + ldsoff) = pk;
    }
#pragma unroll
    for (int rr = 0; rr < 8; ++rr) {
      const int row = half * 8 + rr;
      unsigned short kv = *(const unsigned short*)(cur + row * 512 + (e2 ^ ((row & 7) << 4)));
      num += swp[row] * bf2f(kv);
    }
    __syncthreads();
  }

  num2[t] = num;
  __syncthreads();
  if (t < 256) {
    partials[((size_t)b * NCHUNK + chunk) * 256 + t] = num2[t] + num2[t + 256];
  }
}

// ---------------- combine: den + context + weights per batch ----------------
__global__ void combine_kernel(const float* __restrict__ wexp_g,
                               const float* __restrict__ partials,
                               float* __restrict__ out) {
  __shared__ float red[4];
  __shared__ float rdsh;
  const int b = blockIdx.x, t = threadIdx.x;   // 256 threads
  const float* we = wexp_g + (size_t)b * S_;
  float s = 0.f;
#pragma unroll 4
  for (int i = t; i < S_; i += 256) s += we[i];
#pragma unroll
  for (int mm = 32; mm; mm >>= 1) s += __shfl_xor(s, mm, 64);
  if ((t & 63) == 0) red[t >> 6] = s;
  __syncthreads();
  if (t == 0) rdsh = 1.0f / (red[0] + red[1] + red[2] + red[3]);
  __syncthreads();
  const float rd = rdsh;

  const float* pb = partials + (size_t)b * NCHUNK * 256;
  float num = 0.f;
#pragma unroll 4
  for (int i = 0; i < NCHUNK; ++i) num += pb[i * 256 + t];
  out[b * HE_ + t] = num * rd;

  float* wout = out + B_ * HE_ + (size_t)b * S_;
#pragma unroll 4
  for (int i = t; i < S_; i += 256) wout[i] = we[i] * rd;
}

extern "C" void kernel_launch(void* const* d_in, const int* in_sizes, int n_in,
                              void* d_out, int out_size, void* d_ws, size_t ws_size,
                              hipStream_t stream) {
  const float* query = (const float*)d_in[0];
  const float* keys  = (const float*)d_in[1];
  const float* Wa_w  = (const float*)d_in[2];
  const float* Wa_b  = (const float*)d_in[3];
  const float* Ua_w  = (const float*)d_in[4];
  const float* Ua_b  = (const float*)d_in[5];
  const float* Va_w  = (const float*)d_in[6];
  // Va_b (d_in[7]) is a constant score shift: softmax-invariant, dropped.
  float* out = (float*)d_out;

  char* ws = (char*)d_ws;
  float* qv             = (float*)ws;                               // 32 KB
  unsigned short* ua_bf = (unsigned short*)(ws + 32 * 1024);        // 128 KB
  float* wexp_g         = (float*)(ws + 160 * 1024);                // 1 MB
  float* partials       = (float*)(ws + 160 * 1024 + 1048576);      // 1 MB

  prep_kernel<<<64, 256, 0, stream>>>(query, Wa_w, Wa_b, Ua_w, Ua_b, qv, ua_bf);
  dim3 g(NCHUNK, B_);
  main_kernel<<<g, 512, 0, stream>>>(keys, qv, Va_w, ua_bf, wexp_g, partials);
  combine_kernel<<<B_, 256, 0, stream>>>(wexp_g, partials, out);
}